// Round 8
// baseline (233.296 us; speedup 1.0000x reference)
//
#include <hip/hip_runtime.h>

// LSTM: B=4096, T=256, I=8, H=32, O=1, fp32 in/out, bf16 MFMA compute.
// R8: ANTI-PHASED TILE PAIRS. 256 blocks (1/CU) x 512 threads; block owns 32
// batch rows = 2 independent 16-row tiles (grp 0: waves 0-3, grp 1: waves 4-7).
// Each LSTM step is split at the barrier into two windows:
//   COMPUTE : hfrag = ds_read h(t); acc = MFMA(whh, hfrag, zx)
//   EXCHANGE: act(acc) -> c,h; ds_write h(t+1); zx(t+1) = MFMA(wih, x, bias)
// Tile A computes in even windows, tile B in odd -> each SIMD holds one
// A-wave and one B-wave in OPPOSITE phases: A's ds_read stall is covered by
// B's transcendental issue and vice versa (R5/R7's lockstep left ~60% idle).
// Per-lane j-pair mapping (R4-proven): wave w4 owns j = 8q + 2*w4 + e via
// weight-row perm fr -> n = 32*(fr&3) + 8*(fr>>2) + 2*w4 + e (weights are the
// MFMA FIRST operand) -> accum quad e = gates (i,f,g,o) at (m=L, j).
// x staged per tile in 64-step LDS chunks (steady loop is vm-free; 3 bulk
// restages, each one barrier-drain, amortized). Gate-g rows pre-scaled by
// 2*log2e (others log2e): 5 exp2 + 3 rcp per value.

#define T_LEN   256
#define CH      64    // x chunk timesteps
#define XSTRIDE 130   // shorts per timestep row (16 L x 8 bf16 + 2 pad)
#define LOG2E   1.4426950408889634f

typedef short bf16x8 __attribute__((ext_vector_type(8)));
typedef float f32x4  __attribute__((ext_vector_type(4)));
typedef unsigned u32x4 __attribute__((ext_vector_type(4)));

static __device__ inline short f2bf_rne(float f) {          // one-time (weights)
    union { float f; unsigned u; } v; v.f = f;
    unsigned u = v.u;
    return (short)((u + 0x7FFFu + ((u >> 16) & 1u)) >> 16);
}
static __device__ inline unsigned pack_bf2(float a, float b) {  // low=a, high=b
    union { float f; unsigned u; } x, y; x.f = a; y.f = b;
    return ((x.u + 0x8000u) >> 16) | ((y.u + 0x8000u) & 0xFFFF0000u);
}
static __device__ inline float bf2f(short s) {
    union { unsigned u; float f; } v;
    v.u = ((unsigned)(unsigned short)s) << 16;
    return v.f;
}

__global__ __launch_bounds__(512, 2) void lstm_kernel(
    const float* __restrict__ x, const float* __restrict__ W_ih,
    const float* __restrict__ W_hh, const float* __restrict__ b_ih,
    const float* __restrict__ b_hh, const float* __restrict__ W_out,
    const float* __restrict__ b_out, float* __restrict__ out)
{
    // per-tile x chunk + per-tile h double buffer
    __shared__ __attribute__((aligned(16))) short xl[2][CH * XSTRIDE];     // 33.3 KB
    __shared__ __attribute__((aligned(16))) short h_lds[2][2][16 * 40];    //  5.1 KB

    const int tid   = threadIdx.x;
    const int w     = tid >> 6;        // wave 0..7
    const int grp   = w >> 2;          // tile 0 (A) / 1 (B)
    const int w4    = w & 3;           // wave-in-tile
    const int lane  = tid & 63;
    const int L     = lane & 15;       // batch row in tile / frag row
    const int q     = lane >> 4;       // quad
    const int rbase = blockIdx.x * 32 + grp * 16;   // tile's first batch row
    const int ttid  = tid & 255;       // thread id within tile group
    const float4* xv = (const float4*)x;

    // ---- one-time: weight fragments (FIRST-operand layout [row=L][k=8q+j]) ----
    // frag e row fr=L holds W row n = 32*(L&3) + 8*(L>>2) + 2*w4 + e,
    // scaled by log2e (gate-g rows: 2*log2e, folding tanh's factor 2).
    bf16x8 whh[2], wih[2];
    f32x4  bias[2];
#pragma unroll
    for (int e = 0; e < 2; ++e) {
        const int   n  = 32 * (L & 3) + 8 * (L >> 2) + 2 * w4 + e;
        const float sc = ((L & 3) == 2 ? 2.f * LOG2E : LOG2E);
        const float* src = W_hh + n * 32 + q * 8;
        bf16x8 fr;
#pragma unroll
        for (int j = 0; j < 8; ++j) fr[j] = f2bf_rne(src[j] * sc);
        whh[e] = fr;
        bf16x8 gr = (bf16x8){0,0,0,0,0,0,0,0};
        if (q == 0) {                              // only k=0..7 exist (I=8)
            const float* s2 = W_ih + n * 8;
#pragma unroll
            for (int j = 0; j < 8; ++j) gr[j] = f2bf_rne(s2[j] * sc);
        }
        wih[e] = gr;
        // bias in C-layout: reg r -> row fr=4q+r -> n_r = 32r + 8q + 2w4 + e
        f32x4 bb;
#pragma unroll
        for (int r = 0; r < 4; ++r) {
            const int   nr = 32 * r + 8 * q + 2 * w4 + e;
            const float sr = (r == 2 ? 2.f * LOG2E : LOG2E);
            bb[r] = (b_ih[nr] + b_hh[nr]) * sr;
        }
        bias[e] = bb;
    }

    // zero h buffers
    for (int i = tid; i < 2 * 2 * 16 * 40; i += 512) ((short*)h_lds)[i] = 0;

    // ---- stage chunk 0 (t in [0,64)) for own tile ----
    // positions (tl 0..63, L2 0..15), 4 per thread; 32 B/lane global reads.
#pragma unroll
    for (int it = 0; it < 4; ++it) {
        const int idx = ttid + (it << 8);
        const int tl  = idx & (CH - 1);
        const int L2  = idx >> 6;
        const float4* srcp = xv + ((size_t)(rbase - grp * 16 + grp * 16 + L2) * T_LEN + tl) * 2;
        const float4 a = srcp[0], b = srcp[1];
        u32x4 u;
        u[0] = pack_bf2(a.x, a.y); u[1] = pack_bf2(a.z, a.w);
        u[2] = pack_bf2(b.x, b.y); u[3] = pack_bf2(b.z, b.w);
        *(u32x4*)(&xl[grp][tl * XSTRIDE + L2 * 8]) = u;
    }
    __syncthreads();

    // zx(0) from x(0)
    f32x4 zx[2];
    {
        const bf16x8 xf0 = *(const bf16x8*)(&xl[grp][L * 8]);
        zx[0] = __builtin_amdgcn_mfma_f32_16x16x32_bf16(wih[0], xf0, bias[0], 0, 0, 0);
        zx[1] = __builtin_amdgcn_mfma_f32_16x16x32_bf16(wih[1], xf0, bias[1], 0, 0, 0);
    }

    f32x4 acc0 = {0,0,0,0}, acc1 = {0,0,0,0};
    float c0 = 0.f, c1 = 0.f;

    // ---- window loop: 513 windows in 4 segments, restage between ----
    // A (grp 0): COMPUTE at even s (t=s/2), EXCHANGE at odd s (t=(s-1)/2)
    // B (grp 1): COMPUTE at odd s,        EXCHANGE at even s (skip s=0)
    for (int ck = 0; ck < 4; ++ck) {
        if (ck) {
            // restage chunk ck (t in [64ck, 64ck+63]) for own tile
#pragma unroll
            for (int it = 0; it < 4; ++it) {
                const int idx = ttid + (it << 8);
                const int tl  = idx & (CH - 1);
                const int L2  = idx >> 6;
                const float4* srcp = xv + ((size_t)(rbase + L2) * T_LEN + 64 * ck + tl) * 2;
                const float4 a = srcp[0], b = srcp[1];
                u32x4 u;
                u[0] = pack_bf2(a.x, a.y); u[1] = pack_bf2(a.z, a.w);
                u[2] = pack_bf2(b.x, b.y); u[3] = pack_bf2(b.z, b.w);
                *(u32x4*)(&xl[grp][tl * XSTRIDE + L2 * 8]) = u;
            }
            __syncthreads();   // one-time vm drain per segment
        }
        const int s0 = ck ? (128 * ck - 1) : 0;          // 0, 127, 255, 383
        const int s1 = (ck == 3) ? 512 : (128 * (ck + 1) - 2);  // 126, 254, 382, 512
        for (int s = s0; s <= s1; ++s) {
            if (((s ^ grp) & 1) == 0) {
                // ---- COMPUTE window: t = (s - grp) / 2 ----
                const int t = (s - grp) >> 1;
                if (t < T_LEN) {
                    const bf16x8 hfrag = *(const bf16x8*)(&h_lds[grp][t & 1][L * 40 + q * 8]);
                    acc0 = __builtin_amdgcn_mfma_f32_16x16x32_bf16(whh[0], hfrag, zx[0], 0, 0, 0);
                    acc1 = __builtin_amdgcn_mfma_f32_16x16x32_bf16(whh[1], hfrag, zx[1], 0, 0, 0);
                }
            } else {
                // ---- EXCHANGE window: t = (s - 1 - grp) / 2 ----
                const int t = (s - 1 - grp) >> 1;
                if (t >= 0) {
                    // act: regs r = (i, f, g2, o); g rows pre-doubled.
                    // sig(a)*tanh(b) = (1-eb)*rcp((1+ea)(1+eb)); c-exp clamped.
                    float h0, h1;
                    {
                        const float ei = __builtin_amdgcn_exp2f(-acc0[0]);
                        const float ef = __builtin_amdgcn_exp2f(-acc0[1]);
                        const float eg = __builtin_amdgcn_exp2f(-acc0[2]);
                        const float eo = __builtin_amdgcn_exp2f(-acc0[3]);
                        const float fv = __builtin_amdgcn_rcpf(1.f + ef);
                        const float ig = (1.f - eg) * __builtin_amdgcn_rcpf((1.f + ei) * (1.f + eg));
                        c0 = fmaf(fv, c0, ig);
                        const float ec = __builtin_amdgcn_exp2f(fminf(c0 * (-2.f * LOG2E), 40.f));
                        h0 = (1.f - ec) * __builtin_amdgcn_rcpf((1.f + eo) * (1.f + ec));
                    }
                    {
                        const float ei = __builtin_amdgcn_exp2f(-acc1[0]);
                        const float ef = __builtin_amdgcn_exp2f(-acc1[1]);
                        const float eg = __builtin_amdgcn_exp2f(-acc1[2]);
                        const float eo = __builtin_amdgcn_exp2f(-acc1[3]);
                        const float fv = __builtin_amdgcn_rcpf(1.f + ef);
                        const float ig = (1.f - eg) * __builtin_amdgcn_rcpf((1.f + ei) * (1.f + eg));
                        c1 = fmaf(fv, c1, ig);
                        const float ec = __builtin_amdgcn_exp2f(fminf(c1 * (-2.f * LOG2E), 40.f));
                        h1 = (1.f - ec) * __builtin_amdgcn_rcpf((1.f + eo) * (1.f + ec));
                    }
                    // h(t+1) at (m=L, j=8q+2w4 / +1): adjacent -> single b32
                    *(unsigned*)(&h_lds[grp][(t + 1) & 1][L * 40 + 8 * q + 2 * w4]) = pack_bf2(h0, h1);

                    // zx(t+1) off-chain from staged x
                    int tn = t + 1; if (tn >= T_LEN) tn = T_LEN - 1;
                    const bf16x8 xfrag = *(const bf16x8*)(&xl[grp][(tn & (CH - 1)) * XSTRIDE + L * 8]);
                    zx[0] = __builtin_amdgcn_mfma_f32_16x16x32_bf16(wih[0], xfrag, bias[0], 0, 0, 0);
                    zx[1] = __builtin_amdgcn_mfma_f32_16x16x32_bf16(wih[1], xfrag, bias[1], 0, 0, 0);
                }
            }
            __syncthreads();
        }
    }

    // h(T) = h(256) lives in h_lds[grp][0]
    if (lane < 16 && w4 == 0) {
        float s = b_out[0];
#pragma unroll
        for (int k = 0; k < 32; ++k) s = fmaf(bf2f(h_lds[grp][0][L * 40 + k]), W_out[k], s);
        out[rbase + L] = s;
    }
}

extern "C" void kernel_launch(void* const* d_in, const int* in_sizes, int n_in,
                              void* d_out, int out_size, void* d_ws, size_t ws_size,
                              hipStream_t stream) {
    const float* x     = (const float*)d_in[0];
    const float* W_ih  = (const float*)d_in[1];
    const float* W_hh  = (const float*)d_in[2];
    const float* b_ih  = (const float*)d_in[3];
    const float* b_hh  = (const float*)d_in[4];
    const float* W_out = (const float*)d_in[5];
    const float* b_out = (const float*)d_in[6];
    float* out = (float*)d_out;

    const int B = in_sizes[0] / (T_LEN * 8);  // 4096
    const int blocks = B / 32;                // 256 blocks x 2 tiles
    lstm_kernel<<<blocks, 512, 0, stream>>>(x, W_ih, W_hh, b_ih, b_hh, W_out, b_out, out);
}